// Round 5
// baseline (259.239 us; speedup 1.0000x reference)
//
#include <hip/hip_runtime.h>

#define BB 2
#define SS 2048
#define EE 1024
#define HH 16
#define DD_ 64
#define BH (BB*HH)
#define NQKV (3*EE)
#define MROWS (BB*SS)

typedef _Float16 f16;
typedef _Float16 f16x8 __attribute__((ext_vector_type(8)));
typedef _Float16 f16x4 __attribute__((ext_vector_type(4)));
typedef float f32x4 __attribute__((ext_vector_type(4)));
typedef float f32x16 __attribute__((ext_vector_type(16)));

#define MFMA16(a,b,c) __builtin_amdgcn_mfma_f32_16x16x32_f16(a,b,c,0,0,0)
#define MFMA32(a,b,c) __builtin_amdgcn_mfma_f32_32x32x16_f16(a,b,c,0,0,0)
#define EXP2F(x) __builtin_amdgcn_exp2f(x)
#define LOG2E 1.44269504088896f

__device__ __forceinline__ void gload16(const void* g, void* l) {
    __builtin_amdgcn_global_load_lds(
        (const __attribute__((address_space(1))) void*)g,
        (__attribute__((address_space(3))) void*)l, 16, 0, 0);
}

// ---------------------------------------------------------------------------
// fp32 -> f16 one-shot convert: x (4M), qkv_w (3M), out_w (1M) floats.
// ---------------------------------------------------------------------------
#define NX4  1048576
#define NW14  786432
#define NW24  262144
__global__ __launch_bounds__(256) void cvt_kernel(
    const float* __restrict__ x, const float* __restrict__ w1,
    const float* __restrict__ w2, f16* __restrict__ x16,
    f16* __restrict__ w116, f16* __restrict__ w216)
{
    const int i = blockIdx.x * 256 + threadIdx.x;
    const float* src; f16* dst; int off;
    if (i < NX4)              { src = x;  dst = x16;  off = i; }
    else if (i < NX4 + NW14)  { src = w1; dst = w116; off = i - NX4; }
    else                      { src = w2; dst = w216; off = i - NX4 - NW14; }
    float4 v = ((const float4*)src)[off];
    f16x4 h = { (f16)v.x, (f16)v.y, (f16)v.z, (f16)v.w };
    *(f16x4*)(dst + 4*(size_t)off) = h;
}

// ---------------------------------------------------------------------------
// QKV GEMM, f16 MFMA 16x16x32, 128x128 tile, BK=64, 4 waves.
// ---------------------------------------------------------------------------
__global__ __launch_bounds__(256) void qkv_gemm_kernel(
    const f16* __restrict__ x, const f16* __restrict__ w,
    const float* __restrict__ bias, const float* __restrict__ gates,
    const float* __restrict__ imp, const float* __restrict__ thr,
    f16* __restrict__ q16, f16* __restrict__ k16, f16* __restrict__ v16)
{
    __shared__ f16 As[128*64];
    __shared__ f16 Bs[128*64];
    const int tid  = threadIdx.x;
    const int wave = tid >> 6, lane = tid & 63;
    const int quad = lane >> 4, l15 = lane & 15;
    const int wm = wave & 1, wn = wave >> 1;
    const int m0 = blockIdx.y << 7, n0 = blockIdx.x << 7;

    f32x4 acc[4][4];
#pragma unroll
    for (int i = 0; i < 4; ++i)
#pragma unroll
        for (int j = 0; j < 4; ++j) acc[i][j] = (f32x4){0.f,0.f,0.f,0.f};

    for (int k0 = 0; k0 < EE; k0 += 64) {
        __syncthreads();
#pragma unroll
        for (int u = 0; u < 4; ++u) {
            const int s = tid + (u << 8);
            const int r = s >> 3;
            const int sc = ((s & 7) ^ (r & 7)) << 3;
            gload16(x + (size_t)(m0 + r)*EE + k0 + sc, &As[s << 3]);
            gload16(w + (size_t)(n0 + r)*EE + k0 + sc, &Bs[s << 3]);
        }
        __syncthreads();
#pragma unroll
        for (int ks = 0; ks < 2; ++ks) {
            f16x8 af[4], bf[4];
#pragma unroll
            for (int i = 0; i < 4; ++i) {
                const int r = wm*64 + i*16 + l15;
                af[i] = *(const f16x8*)&As[(r << 6) + ((((ks<<2)+quad) ^ (l15 & 7)) << 3)];
            }
#pragma unroll
            for (int j = 0; j < 4; ++j) {
                const int r = wn*64 + j*16 + l15;
                bf[j] = *(const f16x8*)&Bs[(r << 6) + ((((ks<<2)+quad) ^ (l15 & 7)) << 3)];
            }
#pragma unroll
            for (int i = 0; i < 4; ++i)
#pragma unroll
                for (int j = 0; j < 4; ++j)
                    acc[i][j] = MFMA16(af[i], bf[j], acc[i][j]);
        }
    }

    const int nb    = n0 + wn * 64;
    const int which = nb >> 10;
    const int h     = (nb & 1023) >> 6;
    const float gs   = 1.f / (1.f + __expf(-gates[h] * imp[h]));
    float scale = (gs > thr[0]) ? 1.f : 0.f;
    if (which == 0) scale *= LOG2E;
    f16* __restrict__ dst = (which == 0) ? q16 : ((which == 1) ? k16 : v16);
    float bv[4];
#pragma unroll
    for (int j = 0; j < 4; ++j) bv[j] = bias[nb + j*16 + l15];
#pragma unroll
    for (int i = 0; i < 4; ++i) {
#pragma unroll
        for (int reg = 0; reg < 4; ++reg) {
            const int m = m0 + wm*64 + i*16 + quad*4 + reg;
            const int b = m >> 11, s = m & (SS - 1);
            f16* rowp = dst + (((size_t)(b*HH + h))*SS + s)*DD_ + l15;
#pragma unroll
            for (int j = 0; j < 4; ++j)
                rowp[j*16] = (f16)((acc[i][j][reg] + bv[j]) * scale);
        }
    }
}

// ---------------------------------------------------------------------------
// v transpose [B,H,S,D] -> [B,H,D,S] f16, + vmean (fp32 atomic partials)
// ---------------------------------------------------------------------------
__global__ __launch_bounds__(256) void vtrans_kernel(
    const f16* __restrict__ v16, f16* __restrict__ vt, float* __restrict__ vmean)
{
    __shared__ f16 T[64][74];
    const int tid = threadIdx.x;
    const int bh = blockIdx.y, s0 = blockIdx.x << 6;
#pragma unroll
    for (int u = 0; u < 2; ++u) {
        const int f = tid + (u << 8);
        const int r = f >> 3, c = (f & 7) << 3;
        *(f16x8*)&T[r][c] = *(const f16x8*)(v16 + ((size_t)bh*SS + s0 + r)*DD_ + c);
    }
    __syncthreads();
    const int d = tid >> 2, ch = (tid & 3) << 4;
    union { f16 h[16]; f16x8 v8[2]; } t;
    float ps = 0.f;
#pragma unroll
    for (int u = 0; u < 16; ++u) { f16 val = T[ch + u][d]; t.h[u] = val; ps += (float)val; }
    f16* dp = vt + ((size_t)bh*DD_ + d)*SS + s0 + ch;
    *(f16x8*)(dp)     = t.v8[0];
    *(f16x8*)(dp + 8) = t.v8[1];
    ps += __shfl_xor(ps, 1, 64);
    ps += __shfl_xor(ps, 2, 64);
    if ((tid & 3) == 0) atomicAdd(vmean + bh*DD_ + d, ps * (1.f / SS));
}

// ---------------------------------------------------------------------------
// Flash attention, 32x32x16 MFMA, base-2 softmax. 256 thr = 4 waves; each
// wave owns 64 q-rows (n=2 chunks of 32) so every K/V fragment read from LDS
// feeds 2 MFMAs. K/V tiles register-prefetched (global->reg during compute,
// reg->LDS at iter start) to hide global latency without a vmcnt(0) drain.
// ---------------------------------------------------------------------------
__global__ __launch_bounds__(256) void attn_kernel(
    const f16* __restrict__ q16, const f16* __restrict__ k16,
    const f16* __restrict__ vt, const float* __restrict__ vmean,
    f16* __restrict__ aout)
{
    __shared__ f16 Ks[64*64];          // [key][d], swizzled 16B chunks
    __shared__ f16 Vs[64*64];          // [d][key], swizzled
    __shared__ f16 Ps[4][64*64];       // per-wave P [qrow(64)][key(64)], swizzled
    const int tid  = threadIdx.x;
    const int wave = tid >> 6, lane = tid & 63;
    const int l31 = lane & 31, hi = lane >> 5, l7 = lane & 7;
    const int bh = blockIdx.y, q0 = blockIdx.x << 8;   // 256 q-rows/block
    const f16* qb = q16 + (size_t)bh * SS * DD_;
    const f16* kb = k16 + (size_t)bh * SS * DD_;
    const f16* vb = vt  + (size_t)bh * DD_ * SS;

    // Q fragments (B-operand): chunk n covers qrows q0+wave*64+n*32+l31
    f16x8 qf[2][4];
#pragma unroll
    for (int n = 0; n < 2; ++n)
#pragma unroll
        for (int ks = 0; ks < 4; ++ks)
            qf[n][ks] = *(const f16x8*)(qb +
                (size_t)(q0 + wave*64 + n*32 + l31)*DD_ + ks*16 + hi*8);

    f32x16 accO[2][2];
#pragma unroll
    for (int n = 0; n < 2; ++n)
#pragma unroll
        for (int dt = 0; dt < 2; ++dt)
#pragma unroll
            for (int r = 0; r < 16; ++r) accO[n][dt][r] = 0.f;
    float mold[2] = {-1.0e30f, -1.0e30f}, lsum[2] = {0.f, 0.f};

    // staging: this thread owns chunks tid and tid+256 of each 512-chunk tile
    const int r0 = tid >> 3,          cc0 = tid & 7;
    const int r1 = (tid + 256) >> 3,  cc1 = tid & 7;   // (tid+256)&7 == tid&7
    const int slot0 = (r0 << 6) + ((cc0 ^ (r0 & 7)) << 3);
    const int slot1 = (r1 << 6) + ((cc1 ^ (r1 & 7)) << 3);

    float4 kreg[2], vreg[2];
    kreg[0] = *(const float4*)(kb + (size_t)r0*DD_ + cc0*8);
    kreg[1] = *(const float4*)(kb + (size_t)r1*DD_ + cc1*8);
    vreg[0] = *(const float4*)(vb + (size_t)r0*SS + cc0*8);
    vreg[1] = *(const float4*)(vb + (size_t)r1*SS + cc1*8);

    for (int kt = 0; kt < SS; kt += 64) {
        __syncthreads();               // previous tile fully consumed
        *(float4*)&Ks[slot0] = kreg[0];
        *(float4*)&Ks[slot1] = kreg[1];
        *(float4*)&Vs[slot0] = vreg[0];
        *(float4*)&Vs[slot1] = vreg[1];
        __syncthreads();
        if (kt + 64 < SS) {            // prefetch next tile into regs
            kreg[0] = *(const float4*)(kb + (size_t)(kt + 64 + r0)*DD_ + cc0*8);
            kreg[1] = *(const float4*)(kb + (size_t)(kt + 64 + r1)*DD_ + cc1*8);
            vreg[0] = *(const float4*)(vb + (size_t)r0*SS + kt + 64 + cc0*8);
            vreg[1] = *(const float4*)(vb + (size_t)r1*SS + kt + 64 + cc1*8);
        }

        // S^T[key][qrow]: A = K rows, B = Q^T; kf reused across n
        f32x16 accS[2][2];
#pragma unroll
        for (int n = 0; n < 2; ++n)
#pragma unroll
            for (int mt = 0; mt < 2; ++mt)
#pragma unroll
                for (int r = 0; r < 16; ++r) accS[n][mt][r] = 0.f;
#pragma unroll
        for (int ks = 0; ks < 4; ++ks)
#pragma unroll
            for (int mt = 0; mt < 2; ++mt) {
                f16x8 kf = *(const f16x8*)&Ks[((mt*32 + l31) << 6) +
                                              ((((ks<<1)+hi) ^ l7) << 3)];
#pragma unroll
                for (int n = 0; n < 2; ++n)
                    accS[n][mt] = MFMA32(kf, qf[n][ks], accS[n][mt]);
            }

        // online softmax per chunk (lane holds 32 of 64 keys for its q-row)
#pragma unroll
        for (int n = 0; n < 2; ++n) {
            float mx = -1.0e30f;
#pragma unroll
            for (int mt = 0; mt < 2; ++mt)
#pragma unroll
                for (int r = 0; r < 16; ++r) mx = fmaxf(mx, accS[n][mt][r]);
            mx = fmaxf(mx, __shfl_xor(mx, 32, 64));
            const float mnew = fmaxf(mold[n], mx);
            float sum = 0.f;
#pragma unroll
            for (int mt = 0; mt < 2; ++mt)
#pragma unroll
                for (int r = 0; r < 16; ++r) {
                    float p = EXP2F(accS[n][mt][r] - mnew);
                    accS[n][mt][r] = p; sum += p;
                }
            sum += __shfl_xor(sum, 32, 64);
            const float alpha = EXP2F(mold[n] - mnew);
            lsum[n] = lsum[n] * alpha + sum;
            mold[n] = mnew;
#pragma unroll
            for (int reg = 0; reg < 16; ++reg) {
                const float ar = __shfl(alpha, (reg & 3) + 8*(reg >> 2) + 4*hi, 64);
                accO[n][0][reg] *= ar;
                accO[n][1][reg] *= ar;
            }
            // P -> Ps[qrow = n*32+l31][key], swizzled
#pragma unroll
            for (int mt = 0; mt < 2; ++mt)
#pragma unroll
                for (int g = 0; g < 4; ++g) {
                    f16x4 ph = { (f16)accS[n][mt][g*4+0], (f16)accS[n][mt][g*4+1],
                                 (f16)accS[n][mt][g*4+2], (f16)accS[n][mt][g*4+3] };
                    *(f16x4*)&Ps[wave][((n*32 + l31) << 6) +
                                       ((((mt<<2)+g) ^ l7) << 3) + (hi << 2)] = ph;
                }
        }

        // PV: A = P (per chunk), B = V^T; vf reused across n
        f16x8 af[2][4];
#pragma unroll
        for (int n = 0; n < 2; ++n)
#pragma unroll
            for (int ks = 0; ks < 4; ++ks)
                af[n][ks] = *(const f16x8*)&Ps[wave][((n*32 + l31) << 6) +
                                                    ((((ks<<1)+hi) ^ l7) << 3)];
#pragma unroll
        for (int ks = 0; ks < 4; ++ks)
#pragma unroll
            for (int dt = 0; dt < 2; ++dt) {
                f16x8 vf = *(const f16x8*)&Vs[((dt*32 + l31) << 6) +
                                              ((((ks<<1)+hi) ^ l7) << 3)];
#pragma unroll
                for (int n = 0; n < 2; ++n)
                    accO[n][dt] = MFMA32(af[n][ks], vf, accO[n][dt]);
            }
    }

    const int b = bh >> 4, h = bh & (HH - 1);
    const float vm0 = vmean[bh*DD_ + l31];
    const float vm1 = vmean[bh*DD_ + 32 + l31];
#pragma unroll
    for (int n = 0; n < 2; ++n)
#pragma unroll
        for (int reg = 0; reg < 16; ++reg) {
            const int qr = (reg & 3) + 8*(reg >> 2) + 4*hi;
            const float lf = __shfl(lsum[n], qr, 64);
            const float inv = 1.f / lf;
            const int s = q0 + wave*64 + n*32 + qr;
            f16* op = aout + ((size_t)(b*SS + s))*EE + h*DD_;
            op[l31]      = (f16)(accO[n][0][reg] * inv + vm0);
            op[32 + l31] = (f16)(accO[n][1][reg] * inv + vm1);
        }
}

// ---------------------------------------------------------------------------
// Output GEMM, f16 MFMA, global_load_lds + swizzle: y = a@w^T + b (fp32 out)
// ---------------------------------------------------------------------------
__global__ __launch_bounds__(256) void out_gemm_kernel(
    const f16* __restrict__ a, const f16* __restrict__ w,
    const float* __restrict__ bias, float* __restrict__ y)
{
    __shared__ f16 As[128*64];
    __shared__ f16 Bs[128*64];
    const int tid  = threadIdx.x;
    const int wave = tid >> 6, lane = tid & 63;
    const int quad = lane >> 4, l15 = lane & 15;
    const int wm = wave & 1, wn = wave >> 1;
    const int m0 = blockIdx.y << 7, n0 = blockIdx.x << 7;

    f32x4 acc[4][4];
#pragma unroll
    for (int i = 0; i < 4; ++i)
#pragma unroll
        for (int j = 0; j < 4; ++j) acc[i][j] = (f32x4){0.f,0.f,0.f,0.f};

    for (int k0 = 0; k0 < EE; k0 += 64) {
        __syncthreads();
#pragma unroll
        for (int u = 0; u < 4; ++u) {
            const int s = tid + (u << 8);
            const int r = s >> 3;
            const int sc = ((s & 7) ^ (r & 7)) << 3;
            gload16(a + (size_t)(m0 + r)*EE + k0 + sc, &As[s << 3]);
            gload16(w + (size_t)(n0 + r)*EE + k0 + sc, &Bs[s << 3]);
        }
        __syncthreads();
#pragma unroll
        for (int ks = 0; ks < 2; ++ks) {
            f16x8 af[4], bf[4];
#pragma unroll
            for (int i = 0; i < 4; ++i) {
                const int r = wm*64 + i*16 + l15;
                af[i] = *(const f16x8*)&As[(r << 6) + ((((ks<<2)+quad) ^ (l15 & 7)) << 3)];
            }
#pragma unroll
            for (int j = 0; j < 4; ++j) {
                const int r = wn*64 + j*16 + l15;
                bf[j] = *(const f16x8*)&Bs[(r << 6) + ((((ks<<2)+quad) ^ (l15 & 7)) << 3)];
            }
#pragma unroll
            for (int i = 0; i < 4; ++i)
#pragma unroll
                for (int j = 0; j < 4; ++j)
                    acc[i][j] = MFMA16(af[i], bf[j], acc[i][j]);
        }
    }

    float bv[4];
#pragma unroll
    for (int j = 0; j < 4; ++j) bv[j] = bias[n0 + wn*64 + j*16 + l15];
#pragma unroll
    for (int i = 0; i < 4; ++i) {
#pragma unroll
        for (int reg = 0; reg < 4; ++reg) {
            const int m = m0 + wm*64 + i*16 + quad*4 + reg;
#pragma unroll
            for (int j = 0; j < 4; ++j)
                y[(size_t)m*EE + n0 + wn*64 + j*16 + l15] = acc[i][j][reg] + bv[j];
        }
    }
}

// ---------------------------------------------------------------------------
extern "C" void kernel_launch(void* const* d_in, const int* in_sizes, int n_in,
                              void* d_out, int out_size, void* d_ws, size_t ws_size,
                              hipStream_t stream)
{
    const float* x      = (const float*)d_in[0];
    const float* qkv_w  = (const float*)d_in[1];
    const float* qkv_b  = (const float*)d_in[2];
    const float* out_w  = (const float*)d_in[3];
    const float* out_b  = (const float*)d_in[4];
    const float* gates  = (const float*)d_in[5];
    const float* imp    = (const float*)d_in[6];
    const float* thr    = (const float*)d_in[7];
    float* out = (float*)d_out;

    const size_t TSZ = (size_t)BH * SS * DD_;
    f16* x16  = (f16*)d_ws;
    f16* w116 = x16 + (size_t)MROWS * EE;
    f16* w216 = w116 + (size_t)NQKV * EE;
    f16* q16  = w216 + (size_t)EE * EE;
    f16* k16  = q16 + TSZ;
    f16* v16  = k16 + TSZ;
    f16* vtb  = v16 + TSZ;
    f16* aout = vtb + TSZ;
    float* vmean = (float*)(aout + TSZ);

    hipMemsetAsync(vmean, 0, (size_t)BH * DD_ * sizeof(float), stream);

    cvt_kernel<<<(NX4 + NW14 + NW24) / 256, 256, 0, stream>>>(
        x, qkv_w, out_w, x16, w116, w216);

    dim3 g1(NQKV/128, MROWS/128);   // 24 x 32
    qkv_gemm_kernel<<<g1, 256, 0, stream>>>(x16, w116, qkv_b, gates, imp, thr,
                                            q16, k16, v16);
    dim3 g2(SS/64, BH);             // 32 x 32
    vtrans_kernel<<<g2, 256, 0, stream>>>(v16, vtb, vmean);
    dim3 g2a(SS/256, BH);           // 8 x 32
    attn_kernel<<<g2a, 256, 0, stream>>>(q16, k16, vtb, vmean, aout);
    dim3 g3(EE/128, MROWS/128);     // 8 x 32
    out_gemm_kernel<<<g3, 256, 0, stream>>>(aout, w216, out_b, out);
}

// Round 6
// 230.185 us; speedup vs baseline: 1.1262x; 1.1262x over previous
//
#include <hip/hip_runtime.h>

#define BB 2
#define SS 2048
#define EE 1024
#define HH 16
#define DD_ 64
#define BH (BB*HH)
#define NQKV (3*EE)
#define MROWS (BB*SS)

typedef _Float16 f16;
typedef _Float16 f16x8 __attribute__((ext_vector_type(8)));
typedef _Float16 f16x4 __attribute__((ext_vector_type(4)));
typedef float f32x4 __attribute__((ext_vector_type(4)));
typedef float f32x16 __attribute__((ext_vector_type(16)));

#define MFMA16(a,b,c) __builtin_amdgcn_mfma_f32_16x16x32_f16(a,b,c,0,0,0)
#define MFMA32(a,b,c) __builtin_amdgcn_mfma_f32_32x32x16_f16(a,b,c,0,0,0)
#define EXP2F(x) __builtin_amdgcn_exp2f(x)
#define LOG2E 1.44269504088896f

__device__ __forceinline__ void gload16(const void* g, void* l) {
    __builtin_amdgcn_global_load_lds(
        (const __attribute__((address_space(1))) void*)g,
        (__attribute__((address_space(3))) void*)l, 16, 0, 0);
}

// ---------------------------------------------------------------------------
// fp32 -> f16 one-shot convert: x (4M), qkv_w (3M), out_w (1M) floats.
// ---------------------------------------------------------------------------
#define NX4  1048576
#define NW14  786432
#define NW24  262144
__global__ __launch_bounds__(256) void cvt_kernel(
    const float* __restrict__ x, const float* __restrict__ w1,
    const float* __restrict__ w2, f16* __restrict__ x16,
    f16* __restrict__ w116, f16* __restrict__ w216)
{
    const int i = blockIdx.x * 256 + threadIdx.x;
    const float* src; f16* dst; int off;
    if (i < NX4)              { src = x;  dst = x16;  off = i; }
    else if (i < NX4 + NW14)  { src = w1; dst = w116; off = i - NX4; }
    else                      { src = w2; dst = w216; off = i - NX4 - NW14; }
    float4 v = ((const float4*)src)[off];
    f16x4 h = { (f16)v.x, (f16)v.y, (f16)v.z, (f16)v.w };
    *(f16x4*)(dst + 4*(size_t)off) = h;
}

// ---------------------------------------------------------------------------
// QKV GEMM, f16 MFMA 16x16x32, 128x128 tile, BK=64, 4 waves.
// ---------------------------------------------------------------------------
__global__ __launch_bounds__(256) void qkv_gemm_kernel(
    const f16* __restrict__ x, const f16* __restrict__ w,
    const float* __restrict__ bias, const float* __restrict__ gates,
    const float* __restrict__ imp, const float* __restrict__ thr,
    f16* __restrict__ q16, f16* __restrict__ k16, f16* __restrict__ v16)
{
    __shared__ f16 As[128*64];
    __shared__ f16 Bs[128*64];
    const int tid  = threadIdx.x;
    const int wave = tid >> 6, lane = tid & 63;
    const int quad = lane >> 4, l15 = lane & 15;
    const int wm = wave & 1, wn = wave >> 1;
    const int m0 = blockIdx.y << 7, n0 = blockIdx.x << 7;

    f32x4 acc[4][4];
#pragma unroll
    for (int i = 0; i < 4; ++i)
#pragma unroll
        for (int j = 0; j < 4; ++j) acc[i][j] = (f32x4){0.f,0.f,0.f,0.f};

    for (int k0 = 0; k0 < EE; k0 += 64) {
        __syncthreads();
#pragma unroll
        for (int u = 0; u < 4; ++u) {
            const int s = tid + (u << 8);
            const int r = s >> 3;
            const int sc = ((s & 7) ^ (r & 7)) << 3;
            gload16(x + (size_t)(m0 + r)*EE + k0 + sc, &As[s << 3]);
            gload16(w + (size_t)(n0 + r)*EE + k0 + sc, &Bs[s << 3]);
        }
        __syncthreads();
#pragma unroll
        for (int ks = 0; ks < 2; ++ks) {
            f16x8 af[4], bf[4];
#pragma unroll
            for (int i = 0; i < 4; ++i) {
                const int r = wm*64 + i*16 + l15;
                af[i] = *(const f16x8*)&As[(r << 6) + ((((ks<<2)+quad) ^ (l15 & 7)) << 3)];
            }
#pragma unroll
            for (int j = 0; j < 4; ++j) {
                const int r = wn*64 + j*16 + l15;
                bf[j] = *(const f16x8*)&Bs[(r << 6) + ((((ks<<2)+quad) ^ (l15 & 7)) << 3)];
            }
#pragma unroll
            for (int i = 0; i < 4; ++i)
#pragma unroll
                for (int j = 0; j < 4; ++j)
                    acc[i][j] = MFMA16(af[i], bf[j], acc[i][j]);
        }
    }

    const int nb    = n0 + wn * 64;
    const int which = nb >> 10;
    const int h     = (nb & 1023) >> 6;
    const float gs   = 1.f / (1.f + __expf(-gates[h] * imp[h]));
    float scale = (gs > thr[0]) ? 1.f : 0.f;
    if (which == 0) scale *= LOG2E;
    f16* __restrict__ dst = (which == 0) ? q16 : ((which == 1) ? k16 : v16);
    float bv[4];
#pragma unroll
    for (int j = 0; j < 4; ++j) bv[j] = bias[nb + j*16 + l15];
#pragma unroll
    for (int i = 0; i < 4; ++i) {
#pragma unroll
        for (int reg = 0; reg < 4; ++reg) {
            const int m = m0 + wm*64 + i*16 + quad*4 + reg;
            const int b = m >> 11, s = m & (SS - 1);
            f16* rowp = dst + (((size_t)(b*HH + h))*SS + s)*DD_ + l15;
#pragma unroll
            for (int j = 0; j < 4; ++j)
                rowp[j*16] = (f16)((acc[i][j][reg] + bv[j]) * scale);
        }
    }
}

// ---------------------------------------------------------------------------
// v transpose [B,H,S,D] -> [B,H,D,S] f16, + vmean (fp32 atomic partials)
// ---------------------------------------------------------------------------
__global__ __launch_bounds__(256) void vtrans_kernel(
    const f16* __restrict__ v16, f16* __restrict__ vt, float* __restrict__ vmean)
{
    __shared__ f16 T[64][74];
    const int tid = threadIdx.x;
    const int bh = blockIdx.y, s0 = blockIdx.x << 6;
#pragma unroll
    for (int u = 0; u < 2; ++u) {
        const int f = tid + (u << 8);
        const int r = f >> 3, c = (f & 7) << 3;
        *(f16x8*)&T[r][c] = *(const f16x8*)(v16 + ((size_t)bh*SS + s0 + r)*DD_ + c);
    }
    __syncthreads();
    const int d = tid >> 2, ch = (tid & 3) << 4;
    union { f16 h[16]; f16x8 v8[2]; } t;
    float ps = 0.f;
#pragma unroll
    for (int u = 0; u < 16; ++u) { f16 val = T[ch + u][d]; t.h[u] = val; ps += (float)val; }
    f16* dp = vt + ((size_t)bh*DD_ + d)*SS + s0 + ch;
    *(f16x8*)(dp)     = t.v8[0];
    *(f16x8*)(dp + 8) = t.v8[1];
    ps += __shfl_xor(ps, 1, 64);
    ps += __shfl_xor(ps, 2, 64);
    if ((tid & 3) == 0) atomicAdd(vmean + bh*DD_ + d, ps * (1.f / SS));
}

// ---------------------------------------------------------------------------
// Flash attention, 32x32x16 MFMA, base-2 softmax with WAVE-UNIFORM running
// max (alpha is a scalar -> no per-reg broadcasts; cross-lane ops 18 -> 7
// per iter). 256 thr = 4 waves x 32 q-rows = 128 q-rows/block; grid 512
// blocks = 2 blocks/CU so barrier drains overlap across blocks.
// ---------------------------------------------------------------------------
__global__ __launch_bounds__(256) void attn_kernel(
    const f16* __restrict__ q16, const f16* __restrict__ k16,
    const f16* __restrict__ vt, const float* __restrict__ vmean,
    f16* __restrict__ aout)
{
    __shared__ f16 Ks[64*64];          // [key][d], swizzled 16B chunks
    __shared__ f16 Vs[64*64];          // [d][key], swizzled
    __shared__ f16 Ps[4][32*64];       // per-wave P [qrow][key], swizzled
    const int tid  = threadIdx.x;
    const int wave = tid >> 6, lane = tid & 63;
    const int l31 = lane & 31, hi = lane >> 5, l7 = lane & 7;
    const int bh = blockIdx.y, q0 = blockIdx.x << 7;   // 128 q-rows/block
    const f16* qb = q16 + (size_t)bh * SS * DD_;
    const f16* kb = k16 + (size_t)bh * SS * DD_;
    const f16* vb = vt  + (size_t)bh * DD_ * SS;

    // Q fragments (B-operand): B[k=ks*16+hi*8+j][n=qrow=l31]
    f16x8 qf[4];
#pragma unroll
    for (int ks = 0; ks < 4; ++ks)
        qf[ks] = *(const f16x8*)(qb + (size_t)(q0 + wave*32 + l31)*DD_ + ks*16 + hi*8);

    f32x16 accO[2];
#pragma unroll
    for (int dt = 0; dt < 2; ++dt)
#pragma unroll
        for (int r = 0; r < 16; ++r) accO[dt][r] = 0.f;
    float M = -1.0e30f;     // wave-uniform running max (base-2 domain)
    float lsum = 0.f;       // per-lane: row l31's running sum

    // staging: thread owns 16B chunks tid and tid+256 of each 512-chunk tile
    const int r0 = tid >> 3, r1 = r0 + 32, cc = tid & 7;
    const int sc0 = (cc ^ (r0 & 7)) << 3;
    const int sc1 = (cc ^ (r1 & 7)) << 3;

    for (int kt = 0; kt < SS; kt += 64) {
        __syncthreads();
        gload16(kb + (size_t)(kt + r0)*DD_ + sc0, &Ks[tid << 3]);
        gload16(kb + (size_t)(kt + r1)*DD_ + sc1, &Ks[(tid + 256) << 3]);
        gload16(vb + (size_t)r0*SS + kt + sc0,    &Vs[tid << 3]);
        gload16(vb + (size_t)r1*SS + kt + sc1,    &Vs[(tid + 256) << 3]);
        __syncthreads();

        // S^T[key][qrow]: A = K rows, B = Q^T
        f32x16 accS[2];
#pragma unroll
        for (int mt = 0; mt < 2; ++mt)
#pragma unroll
            for (int r = 0; r < 16; ++r) accS[mt][r] = 0.f;
#pragma unroll
        for (int ks = 0; ks < 4; ++ks)
#pragma unroll
            for (int mt = 0; mt < 2; ++mt) {
                f16x8 kf = *(const f16x8*)&Ks[((mt*32 + l31) << 6) +
                                              ((((ks<<1)+hi) ^ l7) << 3)];
                accS[mt] = MFMA32(kf, qf[ks], accS[mt]);
            }

        // tile max (wave-uniform): lane-local max then 6-stage butterfly
        float mx = -1.0e30f;
#pragma unroll
        for (int mt = 0; mt < 2; ++mt)
#pragma unroll
            for (int r = 0; r < 16; ++r) mx = fmaxf(mx, accS[mt][r]);
        mx = fmaxf(mx, __shfl_xor(mx, 1, 64));
        mx = fmaxf(mx, __shfl_xor(mx, 2, 64));
        mx = fmaxf(mx, __shfl_xor(mx, 4, 64));
        mx = fmaxf(mx, __shfl_xor(mx, 8, 64));
        mx = fmaxf(mx, __shfl_xor(mx, 16, 64));
        mx = fmaxf(mx, __shfl_xor(mx, 32, 64));
        const float mnew = fmaxf(M, mx);
        const float alpha = EXP2F(M - mnew);   // wave-uniform scalar
        M = mnew;
        lsum *= alpha;
#pragma unroll
        for (int r = 0; r < 16; ++r) { accO[0][r] *= alpha; accO[1][r] *= alpha; }

        float sum = 0.f;
#pragma unroll
        for (int mt = 0; mt < 2; ++mt)
#pragma unroll
            for (int r = 0; r < 16; ++r) {
                float p = EXP2F(accS[mt][r] - mnew);
                accS[mt][r] = p; sum += p;
            }
        sum += __shfl_xor(sum, 32, 64);        // combine the two key-halves
        lsum += sum;

        // P -> Ps[qrow=l31][key], swizzled
#pragma unroll
        for (int mt = 0; mt < 2; ++mt)
#pragma unroll
            for (int g = 0; g < 4; ++g) {
                f16x4 ph = { (f16)accS[mt][g*4+0], (f16)accS[mt][g*4+1],
                             (f16)accS[mt][g*4+2], (f16)accS[mt][g*4+3] };
                *(f16x4*)&Ps[wave][(l31 << 6) + ((((mt<<2)+g) ^ l7) << 3) + (hi << 2)] = ph;
            }
        // PV: A = P[qrow][key], B = V^T[d][key]
        f16x8 af[4];
#pragma unroll
        for (int ks = 0; ks < 4; ++ks)
            af[ks] = *(const f16x8*)&Ps[wave][(l31 << 6) + ((((ks<<1)+hi) ^ l7) << 3)];
#pragma unroll
        for (int ks = 0; ks < 4; ++ks)
#pragma unroll
            for (int dt = 0; dt < 2; ++dt) {
                f16x8 vf = *(const f16x8*)&Vs[((dt*32 + l31) << 6) +
                                              ((((ks<<1)+hi) ^ l7) << 3)];
                accO[dt] = MFMA32(af[ks], vf, accO[dt]);
            }
    }

    const int b = bh >> 4, h = bh & (HH - 1);
    const float vm0 = vmean[bh*DD_ + l31];
    const float vm1 = vmean[bh*DD_ + 32 + l31];
#pragma unroll
    for (int reg = 0; reg < 16; ++reg) {
        const int qr = (reg & 3) + 8*(reg >> 2) + 4*hi;
        const float lf = __shfl(lsum, qr, 64);
        const float inv = 1.f / lf;
        const int s = q0 + wave*32 + qr;
        f16* op = aout + ((size_t)(b*SS + s))*EE + h*DD_;
        op[l31]      = (f16)(accO[0][reg] * inv + vm0);
        op[32 + l31] = (f16)(accO[1][reg] * inv + vm1);
    }
}

// ---------------------------------------------------------------------------
// Output GEMM, f16 MFMA, global_load_lds + swizzle: y = a@w^T + b (fp32 out)
// ---------------------------------------------------------------------------
__global__ __launch_bounds__(256) void out_gemm_kernel(
    const f16* __restrict__ a, const f16* __restrict__ w,
    const float* __restrict__ bias, float* __restrict__ y)
{
    __shared__ f16 As[128*64];
    __shared__ f16 Bs[128*64];
    const int tid  = threadIdx.x;
    const int wave = tid >> 6, lane = tid & 63;
    const int quad = lane >> 4, l15 = lane & 15;
    const int wm = wave & 1, wn = wave >> 1;
    const int m0 = blockIdx.y << 7, n0 = blockIdx.x << 7;

    f32x4 acc[4][4];
#pragma unroll
    for (int i = 0; i < 4; ++i)
#pragma unroll
        for (int j = 0; j < 4; ++j) acc[i][j] = (f32x4){0.f,0.f,0.f,0.f};

    for (int k0 = 0; k0 < EE; k0 += 64) {
        __syncthreads();
#pragma unroll
        for (int u = 0; u < 4; ++u) {
            const int s = tid + (u << 8);
            const int r = s >> 3;
            const int sc = ((s & 7) ^ (r & 7)) << 3;
            gload16(a + (size_t)(m0 + r)*EE + k0 + sc, &As[s << 3]);
            gload16(w + (size_t)(n0 + r)*EE + k0 + sc, &Bs[s << 3]);
        }
        __syncthreads();
#pragma unroll
        for (int ks = 0; ks < 2; ++ks) {
            f16x8 af[4], bf[4];
#pragma unroll
            for (int i = 0; i < 4; ++i) {
                const int r = wm*64 + i*16 + l15;
                af[i] = *(const f16x8*)&As[(r << 6) + ((((ks<<2)+quad) ^ (l15 & 7)) << 3)];
            }
#pragma unroll
            for (int j = 0; j < 4; ++j) {
                const int r = wn*64 + j*16 + l15;
                bf[j] = *(const f16x8*)&Bs[(r << 6) + ((((ks<<2)+quad) ^ (l15 & 7)) << 3)];
            }
#pragma unroll
            for (int i = 0; i < 4; ++i)
#pragma unroll
                for (int j = 0; j < 4; ++j)
                    acc[i][j] = MFMA16(af[i], bf[j], acc[i][j]);
        }
    }

    float bv[4];
#pragma unroll
    for (int j = 0; j < 4; ++j) bv[j] = bias[n0 + wn*64 + j*16 + l15];
#pragma unroll
    for (int i = 0; i < 4; ++i) {
#pragma unroll
        for (int reg = 0; reg < 4; ++reg) {
            const int m = m0 + wm*64 + i*16 + quad*4 + reg;
#pragma unroll
            for (int j = 0; j < 4; ++j)
                y[(size_t)m*EE + n0 + wn*64 + j*16 + l15] = acc[i][j][reg] + bv[j];
        }
    }
}

// ---------------------------------------------------------------------------
extern "C" void kernel_launch(void* const* d_in, const int* in_sizes, int n_in,
                              void* d_out, int out_size, void* d_ws, size_t ws_size,
                              hipStream_t stream)
{
    const float* x      = (const float*)d_in[0];
    const float* qkv_w  = (const float*)d_in[1];
    const float* qkv_b  = (const float*)d_in[2];
    const float* out_w  = (const float*)d_in[3];
    const float* out_b  = (const float*)d_in[4];
    const float* gates  = (const float*)d_in[5];
    const float* imp    = (const float*)d_in[6];
    const float* thr    = (const float*)d_in[7];
    float* out = (float*)d_out;

    const size_t TSZ = (size_t)BH * SS * DD_;
    f16* x16  = (f16*)d_ws;
    f16* w116 = x16 + (size_t)MROWS * EE;
    f16* w216 = w116 + (size_t)NQKV * EE;
    f16* q16  = w216 + (size_t)EE * EE;
    f16* k16  = q16 + TSZ;
    f16* v16  = k16 + TSZ;
    f16* vtb  = v16 + TSZ;
    f16* aout = vtb + TSZ;
    float* vmean = (float*)(aout + TSZ);

    hipMemsetAsync(vmean, 0, (size_t)BH * DD_ * sizeof(float), stream);

    cvt_kernel<<<(NX4 + NW14 + NW24) / 256, 256, 0, stream>>>(
        x, qkv_w, out_w, x16, w116, w216);

    dim3 g1(NQKV/128, MROWS/128);   // 24 x 32
    qkv_gemm_kernel<<<g1, 256, 0, stream>>>(x16, w116, qkv_b, gates, imp, thr,
                                            q16, k16, v16);
    dim3 g2(SS/64, BH);             // 32 x 32
    vtrans_kernel<<<g2, 256, 0, stream>>>(v16, vtb, vmean);
    dim3 g2a(SS/128, BH);           // 16 x 32 = 512 blocks (2/CU)
    attn_kernel<<<g2a, 256, 0, stream>>>(q16, k16, vtb, vmean, aout);
    dim3 g3(EE/128, MROWS/128);     // 8 x 32
    out_gemm_kernel<<<g3, 256, 0, stream>>>(aout, w216, out_b, out);
}